// Round 2
// baseline (166.234 us; speedup 1.0000x reference)
//
#include <hip/hip_runtime.h>
#include <hip/hip_bf16.h>

// One thread = one (b,n,m) point. Outputs are FLOAT32 (reference dtype).
// W^T staged in LDS; float4 broadcast reads (same-address -> conflict-free).
__global__ __launch_bounds__(256) void relds_kernel(
    const float* __restrict__ pos,   // [B,N,3]
    const float* __restrict__ tim,   // [B,N]
    const float* __restrict__ W,     // [32,32] row-major W[e][d]
    const float* __restrict__ bias,  // [32]
    float* __restrict__ out_attn,    // f32 [P,32]
    float* __restrict__ out_emb,     // f32 [P,32]
    int N, int NN, int P)
{
    __shared__ float sWt[1024]; // sWt[d*32+e] = W[e][d]
    __shared__ float sb[32];
    const int tid = threadIdx.x;
    #pragma unroll
    for (int k = tid; k < 1024; k += 256)
        sWt[(k & 31) * 32 + (k >> 5)] = W[k];  // coalesced global read
    if (tid < 32) sb[tid] = bias[tid];
    __syncthreads();

    const int p = blockIdx.x * 256 + tid;
    if (p >= P) return;

    const int b  = p / NN;
    const int r  = p - b * NN;
    const int n  = r / N;
    const int m  = r - n * N;
    const int in_n = b * N + n;
    const int in_m = b * N + m;

    const float dx = pos[in_n * 3 + 0] - pos[in_m * 3 + 0];
    const float dy = pos[in_n * 3 + 1] - pos[in_m * 3 + 1];
    const float dz = pos[in_n * 3 + 2] - pos[in_m * 3 + 2];
    const float dt = (tim[in_n] - tim[in_m]) * 18.0f; // TIME_SCALE
    const float ds2 = dx * dx + dy * dy + dz * dz - dt * dt;
    const float d   = copysignf(sqrtf(fabsf(ds2)), ds2);
    const float x   = 1024.0f * fminf(4.0f, fmaxf(-4.0f, d));

    // freqs[i] = 10000^(-i/16) = 10^(-i/4); fold 1/(2pi): v_sin takes revolutions
    constexpr float INV2PI = 0.15915494309189535f;
    constexpr float F[16] = {
        1.0f,    0.5623413251903491f,    0.31622776601683794f,    0.17782794100389228f,
        0.1f,    0.05623413251903491f,   0.031622776601683794f,   0.017782794100389228f,
        0.01f,   0.005623413251903491f,  0.0031622776601683794f,  0.0017782794100389228f,
        0.001f,  0.0005623413251903491f, 0.00031622776601683794f, 0.00017782794100389227f };

    float s[16], c[16];
    #pragma unroll
    for (int i = 0; i < 16; ++i) {
        float rr = x * (F[i] * INV2PI);     // revolutions
        rr -= floorf(rr);                   // reduce to [0,1)
        s[i] = __builtin_amdgcn_sinf(rr);   // sin(2*pi*rr)
        c[i] = __builtin_amdgcn_cosf(rr);
    }

    const size_t eb = (size_t)p * 32;

    // ---- emb output: [sin(0..15), cos(0..15)], 8x float4 stores ----
    float4* emb4 = reinterpret_cast<float4*>(out_emb + eb);
    #pragma unroll
    for (int g = 0; g < 4; ++g)
        emb4[g] = make_float4(s[g*4+0], s[g*4+1], s[g*4+2], s[g*4+3]);
    #pragma unroll
    for (int g = 0; g < 4; ++g)
        emb4[4+g] = make_float4(c[g*4+0], c[g*4+1], c[g*4+2], c[g*4+3]);

    // ---- rel_attn[e] = b[e] + sum_i s[i]*W[e][i] + c[i]*W[e][16+i] ----
    float4* attn4 = reinterpret_cast<float4*>(out_attn + eb);
    #pragma unroll
    for (int eg = 0; eg < 4; ++eg) {
        float acc[8];
        #pragma unroll
        for (int j = 0; j < 8; ++j) acc[j] = sb[eg * 8 + j];
        #pragma unroll
        for (int i = 0; i < 16; ++i) {
            const float4 w0 = *reinterpret_cast<const float4*>(&sWt[i * 32 + eg * 8]);
            const float4 w1 = *reinterpret_cast<const float4*>(&sWt[i * 32 + eg * 8 + 4]);
            const float4 u0 = *reinterpret_cast<const float4*>(&sWt[(16 + i) * 32 + eg * 8]);
            const float4 u1 = *reinterpret_cast<const float4*>(&sWt[(16 + i) * 32 + eg * 8 + 4]);
            const float si = s[i], ci = c[i];
            acc[0] = fmaf(si, w0.x, fmaf(ci, u0.x, acc[0]));
            acc[1] = fmaf(si, w0.y, fmaf(ci, u0.y, acc[1]));
            acc[2] = fmaf(si, w0.z, fmaf(ci, u0.z, acc[2]));
            acc[3] = fmaf(si, w0.w, fmaf(ci, u0.w, acc[3]));
            acc[4] = fmaf(si, w1.x, fmaf(ci, u1.x, acc[4]));
            acc[5] = fmaf(si, w1.y, fmaf(ci, u1.y, acc[5]));
            acc[6] = fmaf(si, w1.z, fmaf(ci, u1.z, acc[6]));
            acc[7] = fmaf(si, w1.w, fmaf(ci, u1.w, acc[7]));
        }
        attn4[eg * 2 + 0] = make_float4(acc[0], acc[1], acc[2], acc[3]);
        attn4[eg * 2 + 1] = make_float4(acc[4], acc[5], acc[6], acc[7]);
    }
}

extern "C" void kernel_launch(void* const* d_in, const int* in_sizes, int n_in,
                              void* d_out, int out_size, void* d_ws, size_t ws_size,
                              hipStream_t stream) {
    const float* pos  = (const float*)d_in[0];
    const float* tim  = (const float*)d_in[1];
    const float* W    = (const float*)d_in[2];
    const float* bias = (const float*)d_in[3];

    // out = concat(rel_attn[B,N,N,32], emb[B,N,N,32]) as f32
    const int BN = in_sizes[1];          // B*N (time element count)
    const int P  = out_size / 64;        // B*N*N
    const int N  = P / BN;               // wait: P/BN = N*... see below
    // P = B*N*N, BN = B*N  =>  P / BN = N
    const int NN = N * N;

    float* out_attn = (float*)d_out;
    float* out_emb  = out_attn + (size_t)out_size / 2;

    const int grid = (P + 255) / 256;
    relds_kernel<<<grid, 256, 0, stream>>>(pos, tim, W, bias, out_attn, out_emb, N, NN, P);
}

// Round 3
// 110.771 us; speedup vs baseline: 1.5007x; 1.5007x over previous
//
#include <hip/hip_runtime.h>
#include <hip/hip_bf16.h>

typedef __bf16 bf16x8 __attribute__((ext_vector_type(8)));
typedef float  f32x4  __attribute__((ext_vector_type(4)));

// freqs[i] = 10000^(-i/16) = 10^(-i/4), i=0..7 (odd k-chunks scale by 1e-2)
__constant__ __device__ const float FREQ8[8] = {
    1.0f, 0.5623413251903491f, 0.31622776601683794f, 0.17782794100389228f,
    0.1f, 0.05623413251903491f, 0.031622776601683794f, 0.017782794100389228f };

// One wave = 64 points. 4 M-tiles x 2 N-tiles of mfma_f32_16x16x32_bf16.
// W^T held in registers as B fragments; no LDS anywhere.
template<bool POW2>
__global__ __launch_bounds__(256) void relds_mfma(
    const float* __restrict__ pos,   // [B,N,3]
    const float* __restrict__ tim,   // [B,N]
    const float* __restrict__ W,     // [32,32] row-major W[e][d]
    const float* __restrict__ bias,  // [32]
    float* __restrict__ out_attn,    // f32 [P,32]
    float* __restrict__ out_emb,     // f32 [P,32]
    int N, int NN, int P, int logN)
{
    const int tid  = threadIdx.x;
    const int lane = tid & 63;
    const int wave = tid >> 6;
    const int row  = lane & 15;   // M-row within tile; also e-col for B/C/D
    const int kb   = lane >> 4;   // k-chunk 0..3

    // ---- B fragments (W^T) + bias, once per block; reads are L1/L2-resident ----
    bf16x8 Bf[2];
    float  bv[2];
    #pragma unroll
    for (int n = 0; n < 2; ++n) {
        const int e = n * 16 + row;
        const float4 wA = *reinterpret_cast<const float4*>(W + e * 32 + kb * 8);
        const float4 wB = *reinterpret_cast<const float4*>(W + e * 32 + kb * 8 + 4);
        Bf[n][0] = (__bf16)wA.x; Bf[n][1] = (__bf16)wA.y;
        Bf[n][2] = (__bf16)wA.z; Bf[n][3] = (__bf16)wA.w;
        Bf[n][4] = (__bf16)wB.x; Bf[n][5] = (__bf16)wB.y;
        Bf[n][6] = (__bf16)wB.z; Bf[n][7] = (__bf16)wB.w;
        bv[n] = bias[e];
    }

    const int wbase = blockIdx.x * 256 + wave * 64;
    if (wbase >= P) return;

    // lane-uniform angle constants: d = kb*8+j; odd chunk -> freqs *1e-2; kb>=2 -> cos
    constexpr float INV2PI = 0.15915494309189535f;
    const float premul = INV2PI * ((kb & 1) ? 0.01f : 1.0f);
    const float qoff   = (kb >= 2) ? 0.25f : 0.0f;   // cos(z) = sin(z + 1/4 rev)

    f32x4 acc[4][2];
    #pragma unroll
    for (int t = 0; t < 4; ++t)
        #pragma unroll
        for (int n = 0; n < 2; ++n)
            #pragma unroll
            for (int r = 0; r < 4; ++r) acc[t][n][r] = bv[n];

    #pragma unroll
    for (int t = 0; t < 4; ++t) {
        const int q  = wbase + t * 16 + row;
        const int qc = (q < P) ? q : (P - 1);
        int in_n, in_m;
        if (POW2) {
            in_n = qc >> logN;
            in_m = ((qc >> (2 * logN)) << logN) | (qc & (N - 1));
        } else {
            const int b_ = qc / NN; const int r_ = qc - b_ * NN;
            const int n_ = r_ / N;  const int m_ = r_ - n_ * N;
            in_n = b_ * N + n_;     in_m = b_ * N + m_;
        }
        const float dx = pos[in_n * 3 + 0] - pos[in_m * 3 + 0];
        const float dy = pos[in_n * 3 + 1] - pos[in_m * 3 + 1];
        const float dz = pos[in_n * 3 + 2] - pos[in_m * 3 + 2];
        const float dt = (tim[in_n] - tim[in_m]) * 18.0f;  // TIME_SCALE
        const float ds2 = dx * dx + dy * dy + dz * dz - dt * dt;
        const float d   = copysignf(sqrtf(fabsf(ds2)), ds2);
        const float x   = 1024.0f * fminf(4.0f, fmaxf(-4.0f, d));
        const float xr  = x * premul;   // revolutions, pre-scaled per k-chunk

        float v[8];
        #pragma unroll
        for (int j = 0; j < 8; ++j) {
            float rr = fmaf(xr, FREQ8[j], qoff);
            rr -= floorf(rr);
            v[j] = __builtin_amdgcn_sinf(rr);
        }

        if (q < P) {  // emb out: this lane owns dims kb*8..kb*8+7 of point q
            float* ep = out_emb + (size_t)q * 32 + kb * 8;
            reinterpret_cast<float4*>(ep)[0] = make_float4(v[0], v[1], v[2], v[3]);
            reinterpret_cast<float4*>(ep)[1] = make_float4(v[4], v[5], v[6], v[7]);
        }

        bf16x8 Af;
        #pragma unroll
        for (int j = 0; j < 8; ++j) Af[j] = (__bf16)v[j];
        acc[t][0] = __builtin_amdgcn_mfma_f32_16x16x32_bf16(Af, Bf[0], acc[t][0], 0, 0, 0);
        acc[t][1] = __builtin_amdgcn_mfma_f32_16x16x32_bf16(Af, Bf[1], acc[t][1], 0, 0, 0);
    }

    // ---- rel_attn stores: C/D layout col=lane&15, row=(lane>>4)*4+reg ----
    #pragma unroll
    for (int t = 0; t < 4; ++t) {
        const int prow = wbase + t * 16 + kb * 4;
        #pragma unroll
        for (int n = 0; n < 2; ++n) {
            #pragma unroll
            for (int r = 0; r < 4; ++r) {
                if (prow + r < P)
                    out_attn[(size_t)(prow + r) * 32 + n * 16 + row] = acc[t][n][r];
            }
        }
    }
}

extern "C" void kernel_launch(void* const* d_in, const int* in_sizes, int n_in,
                              void* d_out, int out_size, void* d_ws, size_t ws_size,
                              hipStream_t stream) {
    const float* pos  = (const float*)d_in[0];
    const float* tim  = (const float*)d_in[1];
    const float* W    = (const float*)d_in[2];
    const float* bias = (const float*)d_in[3];

    const int BN = in_sizes[1];          // B*N
    const int P  = out_size / 64;        // B*N*N
    const int N  = P / BN;
    const int NN = N * N;

    int logN = 0;
    while ((1 << logN) < N) ++logN;
    const bool pow2 = ((1 << logN) == N);

    float* out_attn = (float*)d_out;
    float* out_emb  = out_attn + (size_t)out_size / 2;

    const int grid = (P + 255) / 256;
    if (pow2)
        relds_mfma<true><<<grid, 256, 0, stream>>>(pos, tim, W, bias, out_attn, out_emb, N, NN, P, logN);
    else
        relds_mfma<false><<<grid, 256, 0, stream>>>(pos, tim, W, bias, out_attn, out_emb, N, NN, P, logN);
}